// Round 13
// baseline (819.983 us; speedup 1.0000x reference)
//
#include <hip/hip_runtime.h>
#include <hip/hip_bf16.h>

#define EMBED 300
#define HD    128
#define LLEN  512
#define G4    512   // 4*H

// Workspace layout (floats):
// preg [2][4][512][512] @0 (dead after k2; k45a partials reuse it)
#define OFF_LSTM 2097152
#define OFF_PROJ 2621440
#define OFF_MX   3145728

typedef _Float16 half8 __attribute__((ext_vector_type(8)));
typedef float    f32x4 __attribute__((ext_vector_type(4)));

__device__ __forceinline__ float fsig(float x) {
    return __fdividef(1.f, 1.f + __expf(-x));
}
__device__ __forceinline__ float ftanh(float x) {
    return 1.f - __fdividef(2.f, __expf(2.f * x) + 1.f);
}

// ---------------- K1: embedding gather + X @ W_ih + b  → pre_g ----------------
__global__ __launch_bounds__(256) void k1_gemm(
    const int* __restrict__ qc, const int* __restrict__ ac,
    const float* __restrict__ emb, const float* __restrict__ wih,
    const float* __restrict__ bl, float* __restrict__ preg)
{
    __shared__ float As[32][65];
    __shared__ float Bs[32][64];
    const int m0 = blockIdx.x * 64;
    const int n0 = blockIdx.y * 64;
    const int tid = threadIdx.x;
    const int tx = tid & 15, ty = tid >> 4;
    float acc[4][4] = {};

    for (int k0 = 0; k0 < 300; k0 += 32) {
        #pragma unroll
        for (int i = 0; i < 8; ++i) {
            int e = tid + i * 256;
            int m = e >> 5, kk = e & 31;
            int row = m0 + m;
            int c = row >> 11, b = (row >> 9) & 3, t = row & 511;
            int tok = (c == 0 ? qc : ac)[b * LLEN + t];
            int k = k0 + kk;
            As[kk][m] = (k < 300) ? emb[(size_t)tok * EMBED + k] : 0.f;
        }
        #pragma unroll
        for (int i = 0; i < 8; ++i) {
            int e = tid + i * 256;
            int kk = e >> 6, n = e & 63;
            int k = k0 + kk;
            Bs[kk][n] = (k < 300) ? wih[k * G4 + n0 + n] : 0.f;
        }
        __syncthreads();
        #pragma unroll
        for (int kk = 0; kk < 32; ++kk) {
            float a[4], bv[4];
            #pragma unroll
            for (int i = 0; i < 4; ++i) a[i] = As[kk][ty * 4 + i];
            #pragma unroll
            for (int j = 0; j < 4; ++j) bv[j] = Bs[kk][tx * 4 + j];
            #pragma unroll
            for (int i = 0; i < 4; ++i)
                #pragma unroll
                for (int j = 0; j < 4; ++j)
                    acc[i][j] += a[i] * bv[j];
        }
        __syncthreads();
    }
    #pragma unroll
    for (int i = 0; i < 4; ++i) {
        int row = m0 + ty * 4 + i;
        #pragma unroll
        for (int j = 0; j < 4; ++j) {
            int n = n0 + tx * 4 + j;
            preg[(size_t)row * G4 + n] = acc[i][j] + bl[n];
        }
    }
}

// ---------------- K2: MFMA LSTM scan, TWO sequences per WG (TLP packing). 4 WGs ----------------
// Each 512-thread half runs the proven round-9 scan on its own sequence + own LDS
// hist. 4 waves/SIMD from 2 independent recurrences fill each other's latency
// windows. One WG-wide barrier per step (halves in harmless lockstep).
__global__ __launch_bounds__(1024, 1) void k2_lstm_mfma(
    const float* __restrict__ whh, const float* __restrict__ preg,
    const float* __restrict__ wa,
    float* __restrict__ lstm, float* __restrict__ proj, float* __restrict__ mx)
{
    const int half = threadIdx.x >> 9;   // 0 or 1
    const int seq  = blockIdx.x * 2 + half;   // 0..7
    const int tid  = threadIdx.x & 511;
    const int w  = tid >> 6;             // wave-in-half 0..7
    const int l  = tid & 63;
    const int li = l & 15;
    const int g  = l >> 4;

    __shared__ __align__(16) _Float16 hist[2][32 * 136];   // per-half h ring
    _Float16* hst = hist[half];

    // static gate A fragments: A[m=li][k=kt*32+g*8+e] = Whh[k][mg], mg = s*128+w*16+li
    half8 afrag[4][4];
    #pragma unroll
    for (int s = 0; s < 4; ++s) {
        const int mg = s * 128 + w * 16 + li;
        #pragma unroll
        for (int kt = 0; kt < 4; ++kt) {
            half8 v;
            #pragma unroll
            for (int e = 0; e < 8; ++e)
                v[e] = (_Float16)whh[(kt * 32 + g * 8 + e) * G4 + mg];
            afrag[kt][s] = v;
        }
    }
    // static proj A fragments: A[m=li][k] = Wa[s_side*128 + k][w*16+li]
    const int s_side = seq >> 2;
    half8 afragW[4];
    #pragma unroll
    for (int kt = 0; kt < 4; ++kt) {
        half8 v;
        #pragma unroll
        for (int e = 0; e < 8; ++e)
            v[e] = (_Float16)wa[(s_side * 128 + kt * 32 + g * 8 + e) * 128 + (w * 16 + li)];
        afragW[kt] = v;
    }

    for (int i = tid; i < 32 * 68; i += 512) ((unsigned*)hst)[i] = 0u;

    const f32x4* pg4 = (const f32x4*)(preg + (size_t)seq * LLEN * G4);
    const int pgo = w * 4 + g;           // f32x4 idx; + t*128 + s*32
    const int r   = li & 3;
    const int unit = w * 16 + g * 4 + r;
    const bool wlane = li < 4;
    float* outp = lstm + (size_t)seq * LLEN * HD + unit;
    float cst = 0.f;
    float pmr0 = -1e30f, pmr1 = -1e30f, pmr2 = -1e30f, pmr3 = -1e30f;

    f32x4 pgA[4], pgB[4];
    #pragma unroll
    for (int s = 0; s < 4; ++s) pgA[s] = pg4[0 * 128 + s * 32 + pgo];
    #pragma unroll
    for (int s = 0; s < 4; ++s) pgB[s] = pg4[1 * 128 + s * 32 + pgo];

    __syncthreads();

#define LSTM_STEP(T, PGV, RDS, WRS)                                            \
    {                                                                          \
        half8 bfrag[4];                                                        \
        _Pragma("unroll")                                                      \
        for (int kt = 0; kt < 4; ++kt)                                         \
            bfrag[kt] = *(const half8*)(hst + (RDS) * 136 + kt * 32 + g * 8);  \
        f32x4 a0 = PGV[0], a1 = PGV[1], a2 = PGV[2], a3 = PGV[3];              \
        {                                                                      \
            int tp = (T) + 2; if (tp > 511) tp = 511;                          \
            _Pragma("unroll")                                                  \
            for (int s = 0; s < 4; ++s) PGV[s] = pg4[tp * 128 + s * 32 + pgo]; \
        }                                                                      \
        _Pragma("unroll")                                                      \
        for (int kt = 0; kt < 4; ++kt) {                                       \
            a0 = __builtin_amdgcn_mfma_f32_16x16x32_f16(afrag[kt][0], bfrag[kt], a0, 0, 0, 0); \
            a1 = __builtin_amdgcn_mfma_f32_16x16x32_f16(afrag[kt][1], bfrag[kt], a1, 0, 0, 0); \
            a2 = __builtin_amdgcn_mfma_f32_16x16x32_f16(afrag[kt][2], bfrag[kt], a2, 0, 0, 0); \
            a3 = __builtin_amdgcn_mfma_f32_16x16x32_f16(afrag[kt][3], bfrag[kt], a3, 0, 0, 0); \
        }                                                                      \
        float xi = (r == 0) ? a0[0] : (r == 1) ? a0[1] : (r == 2) ? a0[2] : a0[3]; \
        float xf = (r == 0) ? a1[0] : (r == 1) ? a1[1] : (r == 2) ? a1[2] : a1[3]; \
        float xg = (r == 0) ? a2[0] : (r == 1) ? a2[1] : (r == 2) ? a2[2] : a2[3]; \
        float xo = (r == 0) ? a3[0] : (r == 1) ? a3[1] : (r == 2) ? a3[2] : a3[3]; \
        float i_ = fsig(xi), f_ = fsig(xf), g_ = ftanh(xg), o_ = fsig(xo);     \
        cst = f_ * cst + i_ * g_;                                              \
        float h = o_ * ftanh(cst);                                             \
        if (wlane) {                                                           \
            outp[(size_t)(T) * HD] = h;                                        \
            hst[(WRS) * 136 + unit] = (_Float16)h;                             \
        }                                                                      \
        asm volatile("s_waitcnt lgkmcnt(0)" ::: "memory");                     \
        __builtin_amdgcn_sched_barrier(0);                                     \
        __builtin_amdgcn_s_barrier();                                          \
        __builtin_amdgcn_sched_barrier(0);                                     \
    }

#define PROJ_BATCH(P, TBASE)                                                   \
    {                                                                          \
        const _Float16* hb = hst + ((P) * 16 + li) * 136 + g * 8;              \
        half8 bb0 = *(const half8*)(hb + 0 * 32);                              \
        half8 bb1 = *(const half8*)(hb + 1 * 32);                              \
        half8 bb2 = *(const half8*)(hb + 2 * 32);                              \
        half8 bb3 = *(const half8*)(hb + 3 * 32);                              \
        f32x4 pa = {0.f, 0.f, 0.f, 0.f};                                       \
        pa = __builtin_amdgcn_mfma_f32_16x16x32_f16(afragW[0], bb0, pa, 0, 0, 0); \
        pa = __builtin_amdgcn_mfma_f32_16x16x32_f16(afragW[1], bb1, pa, 0, 0, 0); \
        pa = __builtin_amdgcn_mfma_f32_16x16x32_f16(afragW[2], bb2, pa, 0, 0, 0); \
        pa = __builtin_amdgcn_mfma_f32_16x16x32_f16(afragW[3], bb3, pa, 0, 0, 0); \
        float* pp = proj + (size_t)seq * LLEN * HD                             \
                  + (size_t)((TBASE) + li) * HD + w * 16 + g * 4;              \
        *(f32x4*)pp = pa;                                                      \
        pmr0 = fmaxf(pmr0, pa[0]);                                             \
        pmr1 = fmaxf(pmr1, pa[1]);                                             \
        pmr2 = fmaxf(pmr2, pa[2]);                                             \
        pmr3 = fmaxf(pmr3, pa[3]);                                             \
    }

    #pragma unroll 1
    for (int tt = 0; tt < 256; ++tt) {
        const int t0 = tt * 2;
        const int s0 = t0 & 31;
        LSTM_STEP(t0,     pgA, (s0 + 31) & 31, s0);
        LSTM_STEP(t0 + 1, pgB, s0, s0 + 1);
        if ((tt & 7) == 7) {
            const int p = (tt >> 3) & 1;
            PROJ_BATCH(p, t0 - 14);
        }
    }
#undef LSTM_STEP
#undef PROJ_BATCH

    // mx: reduce running max over the 16 li lanes (time slices), store per row
    #pragma unroll
    for (int m = 1; m <= 8; m <<= 1) {
        pmr0 = fmaxf(pmr0, __shfl_xor(pmr0, m, 64));
        pmr1 = fmaxf(pmr1, __shfl_xor(pmr1, m, 64));
        pmr2 = fmaxf(pmr2, __shfl_xor(pmr2, m, 64));
        pmr3 = fmaxf(pmr3, __shfl_xor(pmr3, m, 64));
    }
    if (li == 0) {
        mx[seq * HD + w * 16 + g * 4 + 0] = pmr0;
        mx[seq * HD + w * 16 + g * 4 + 1] = pmr1;
        mx[seq * HD + w * 16 + g * 4 + 2] = pmr2;
        mx[seq * HD + w * 16 + g * 4 + 3] = pmr3;
    }
}

// ---------------- K45a: partial one-pass attention. 32 WGs ----------------
__global__ __launch_bounds__(512) void k45a_attn(
    const float* __restrict__ lstm, const float* __restrict__ proj,
    const float* __restrict__ mx, const float* __restrict__ ba,
    const float* __restrict__ wq, const float* __restrict__ wans,
    float* __restrict__ pn, float* __restrict__ pd)
{
    const int bid = blockIdx.x;          // 0..31
    const int chunk = bid & 3, sb = bid >> 2;
    const int s = sb >> 2, b = sb & 3;
    const int tid = threadIdx.x;
    const int wave = tid >> 6, lane = tid & 63;

    __shared__ float nred[8][128];
    __shared__ float dred[8];

    const float* wv = (s == 0) ? wq : wans;
    const float* lb = lstm + (size_t)sb * LLEN * HD;
    const float* po = proj + (size_t)((1 - s) * 4 + b) * LLEN * HD;

    const float mb1 = mx[sb * HD + lane] + ba[lane];
    const float mb2 = mx[sb * HD + lane + 64] + ba[lane + 64];
    const float wv1a = wv[lane], wv1b = wv[lane + 64];
    const float wv2a = wv[128 + lane], wv2b = wv[192 + lane];

    float n1 = 0.f, n2 = 0.f, den = 0.f;
    #pragma unroll 4
    for (int jj = 0; jj < 16; ++jj) {
        const int j = chunk * 128 + wave + jj * 8;
        float L1 = lb[(size_t)j * HD + lane];
        float L2 = lb[(size_t)j * HD + lane + 64];
        float P1 = po[(size_t)j * HD + lane];
        float P2 = po[(size_t)j * HD + lane + 64];
        float r1 = ftanh(mb1 + P1), r2 = ftanh(mb2 + P2);
        float sc = L1 * wv1a + L2 * wv1b + r1 * wv2a + r2 * wv2b;
        #pragma unroll
        for (int o = 32; o; o >>= 1) sc += __shfl_xor(sc, o, 64);
        float e = __expf(sc);
        den += e;
        n1 += e * r1;
        n2 += e * r2;
    }
    nred[wave][lane] = n1;
    nred[wave][lane + 64] = n2;
    if (lane == 0) dred[wave] = den;
    __syncthreads();

    if (tid < 128) {
        float s8 = 0.f;
        #pragma unroll
        for (int i = 0; i < 8; ++i) s8 += nred[i][tid];
        pn[bid * 128 + tid] = s8;
    }
    if (tid == 128) {
        float dd = 0.f;
        #pragma unroll
        for (int i = 0; i < 8; ++i) dd += dred[i];
        pd[bid] = dd;
    }
}

// ---------------- K45b: merge partials + classifier + log_softmax. 4 WGs ----------------
__global__ __launch_bounds__(256) void k45b_final(
    const float* __restrict__ pn, const float* __restrict__ pd,
    const float* __restrict__ wlast, const float* __restrict__ blast,
    float* __restrict__ outp)
{
    const int b = blockIdx.x;            // 0..3
    const int tid = threadIdx.x;
    __shared__ float feats[2][128];
    __shared__ float cls[256];

    {
        const int ss = tid >> 7, h = tid & 127;
        const int base = (ss * 4 + b) * 4;
        float num = pn[(base + 0) * 128 + h] + pn[(base + 1) * 128 + h]
                  + pn[(base + 2) * 128 + h] + pn[(base + 3) * 128 + h];
        float dd  = pd[base + 0] + pd[base + 1] + pd[base + 2] + pd[base + 3];
        feats[ss][h] = num / dd;
    }
    __syncthreads();

    if (tid < 128) {
        float f0 = feats[0][tid], f1 = feats[1][tid];
        cls[tid]       = f0 * wlast[tid * 2 + 0] + f1 * wlast[(128 + tid) * 2 + 0];
        cls[128 + tid] = f0 * wlast[tid * 2 + 1] + f1 * wlast[(128 + tid) * 2 + 1];
    }
    __syncthreads();
    if (tid < 64) {
        float a0 = cls[tid] + cls[tid + 64];
        float a1 = cls[128 + tid] + cls[192 + tid];
        #pragma unroll
        for (int o = 32; o; o >>= 1) {
            a0 += __shfl_down(a0, o, 64);
            a1 += __shfl_down(a1, o, 64);
        }
        if (tid == 0) {
            float l0 = blast[0] + a0, l1 = blast[1] + a1;
            float mxl = fmaxf(l0, l1);
            float lse = mxl + logf(__expf(l0 - mxl) + __expf(l1 - mxl));
            outp[b * 2 + 0] = l0 - lse;
            outp[b * 2 + 1] = l1 - lse;
            outp[8 + b]     = (l1 > l0) ? 1.f : 0.f;
        }
    }
}

extern "C" void kernel_launch(void* const* d_in, const int* in_sizes, int n_in,
                              void* d_out, int out_size, void* d_ws, size_t ws_size,
                              hipStream_t stream)
{
    const int*   qc    = (const int*)d_in[0];
    const int*   ac    = (const int*)d_in[1];
    const float* emb   = (const float*)d_in[2];
    const float* wih   = (const float*)d_in[3];
    const float* whh   = (const float*)d_in[4];
    const float* bl    = (const float*)d_in[5];
    const float* wa    = (const float*)d_in[6];
    const float* ba    = (const float*)d_in[7];
    const float* wq    = (const float*)d_in[8];
    const float* wans  = (const float*)d_in[10];
    const float* wlast = (const float*)d_in[12];
    const float* blast = (const float*)d_in[13];

    float* ws   = (float*)d_ws;
    float* preg = ws;
    float* lstm = ws + OFF_LSTM;
    float* proj = ws + OFF_PROJ;
    float* mx   = ws + OFF_MX;
    float* pn   = ws;          // preg region is dead after k2
    float* pd   = ws + 4096;

    k1_gemm<<<dim3(64, 8), 256, 0, stream>>>(qc, ac, emb, wih, bl, preg);
    k2_lstm_mfma<<<4, 1024, 0, stream>>>(whh, preg, wa, lstm, proj, mx);
    k45a_attn<<<32, 512, 0, stream>>>(lstm, proj, mx, ba, wq, wans, pn, pd);
    k45b_final<<<4, 256, 0, stream>>>(pn, pd, wlast, blast, (float*)d_out);
}

// Round 14
// 381.847 us; speedup vs baseline: 2.1474x; 2.1474x over previous
//
#include <hip/hip_runtime.h>
#include <hip/hip_bf16.h>

#define EMBED 300
#define HD    128
#define LLEN  512
#define G4    512   // 4*H

// Workspace layout (floats):
// preg [2][4][512][512] @0 (dead after k2; k45a partials reuse it)
#define OFF_LSTM 2097152
#define OFF_PROJ 2621440
#define OFF_MX   3145728

typedef _Float16 half8 __attribute__((ext_vector_type(8)));
typedef float    f32x4 __attribute__((ext_vector_type(4)));

__device__ __forceinline__ float fsig(float x) {
    return __fdividef(1.f, 1.f + __expf(-x));
}
__device__ __forceinline__ float ftanh(float x) {
    return 1.f - __fdividef(2.f, __expf(2.f * x) + 1.f);
}

// ---------------- K1: embedding gather + X @ W_ih + b  → pre_g ----------------
__global__ __launch_bounds__(256) void k1_gemm(
    const int* __restrict__ qc, const int* __restrict__ ac,
    const float* __restrict__ emb, const float* __restrict__ wih,
    const float* __restrict__ bl, float* __restrict__ preg)
{
    __shared__ float As[32][65];
    __shared__ float Bs[32][64];
    const int m0 = blockIdx.x * 64;
    const int n0 = blockIdx.y * 64;
    const int tid = threadIdx.x;
    const int tx = tid & 15, ty = tid >> 4;
    float acc[4][4] = {};

    for (int k0 = 0; k0 < 300; k0 += 32) {
        #pragma unroll
        for (int i = 0; i < 8; ++i) {
            int e = tid + i * 256;
            int m = e >> 5, kk = e & 31;
            int row = m0 + m;
            int c = row >> 11, b = (row >> 9) & 3, t = row & 511;
            int tok = (c == 0 ? qc : ac)[b * LLEN + t];
            int k = k0 + kk;
            As[kk][m] = (k < 300) ? emb[(size_t)tok * EMBED + k] : 0.f;
        }
        #pragma unroll
        for (int i = 0; i < 8; ++i) {
            int e = tid + i * 256;
            int kk = e >> 6, n = e & 63;
            int k = k0 + kk;
            Bs[kk][n] = (k < 300) ? wih[k * G4 + n0 + n] : 0.f;
        }
        __syncthreads();
        #pragma unroll
        for (int kk = 0; kk < 32; ++kk) {
            float a[4], bv[4];
            #pragma unroll
            for (int i = 0; i < 4; ++i) a[i] = As[kk][ty * 4 + i];
            #pragma unroll
            for (int j = 0; j < 4; ++j) bv[j] = Bs[kk][tx * 4 + j];
            #pragma unroll
            for (int i = 0; i < 4; ++i)
                #pragma unroll
                for (int j = 0; j < 4; ++j)
                    acc[i][j] += a[i] * bv[j];
        }
        __syncthreads();
    }
    #pragma unroll
    for (int i = 0; i < 4; ++i) {
        int row = m0 + ty * 4 + i;
        #pragma unroll
        for (int j = 0; j < 4; ++j) {
            int n = n0 + tx * 4 + j;
            preg[(size_t)row * G4 + n] = acc[i][j] + bl[n];
        }
    }
}

// ---------------- K2: MFMA LSTM scan + 16-step-batched proj. 8 WGs ----------------
// Round-11 structure (best), with lane-parallel gate nonlinearity:
// lane (g,li) applies the activation for gate s=li>>2, elem e=li&3 (1 exp+1 rcp);
// owners (li<4) gather f,g,o via shfl_xor(4/8/12). Bit-identical formulas.
__global__ __launch_bounds__(512, 1) void k2_lstm_mfma(
    const float* __restrict__ whh, const float* __restrict__ preg,
    const float* __restrict__ wa,
    float* __restrict__ lstm, float* __restrict__ proj, float* __restrict__ mx)
{
    const int seq = blockIdx.x;          // c*4 + b, 0..7
    const int tid = threadIdx.x;
    const int w  = tid >> 6;             // wave 0..7
    const int l  = tid & 63;
    const int li = l & 15;
    const int g  = l >> 4;

    __shared__ __align__(16) _Float16 hist[32 * 136];   // padded rows

    // static gate A fragments: A[m=li][k=kt*32+g*8+e] = Whh[k][mg], mg = s*128+w*16+li
    half8 afrag[4][4];
    #pragma unroll
    for (int s = 0; s < 4; ++s) {
        const int mg = s * 128 + w * 16 + li;
        #pragma unroll
        for (int kt = 0; kt < 4; ++kt) {
            half8 v;
            #pragma unroll
            for (int e = 0; e < 8; ++e)
                v[e] = (_Float16)whh[(kt * 32 + g * 8 + e) * G4 + mg];
            afrag[kt][s] = v;
        }
    }
    // static proj A fragments: A[m=li][k] = Wa[s_side*128 + k][w*16+li]
    const int s_side = seq >> 2;
    half8 afragW[4];
    #pragma unroll
    for (int kt = 0; kt < 4; ++kt) {
        half8 v;
        #pragma unroll
        for (int e = 0; e < 8; ++e)
            v[e] = (_Float16)wa[(s_side * 128 + kt * 32 + g * 8 + e) * 128 + (w * 16 + li)];
        afragW[kt] = v;
    }

    for (int i = tid; i < 32 * 68; i += 512) ((unsigned*)hist)[i] = 0u;

    const f32x4* pg4 = (const f32x4*)(preg + (size_t)seq * LLEN * G4);
    const int pgo = w * 4 + g;           // f32x4 idx; + t*128 + s*32
    const int r   = li & 3;              // element e
    const int sgate = li >> 2;           // gate this lane activates
    const bool isg = (sgate == 2);       // tanh gate?
    const int unit = w * 16 + g * 4 + r;
    const bool wlane = li < 4;
    float* outp = lstm + (size_t)seq * LLEN * HD + unit;
    float cst = 0.f;
    float pmr0 = -1e30f, pmr1 = -1e30f, pmr2 = -1e30f, pmr3 = -1e30f;

    f32x4 pgA[4], pgB[4];
    #pragma unroll
    for (int s = 0; s < 4; ++s) pgA[s] = pg4[0 * 128 + s * 32 + pgo];
    #pragma unroll
    for (int s = 0; s < 4; ++s) pgB[s] = pg4[1 * 128 + s * 32 + pgo];

    __syncthreads();

#define LSTM_STEP(T, PGV, RDS, WRS)                                            \
    {                                                                          \
        half8 bfrag[4];                                                        \
        _Pragma("unroll")                                                      \
        for (int kt = 0; kt < 4; ++kt)                                         \
            bfrag[kt] = *(const half8*)(hist + (RDS) * 136 + kt * 32 + g * 8); \
        f32x4 a0 = PGV[0], a1 = PGV[1], a2 = PGV[2], a3 = PGV[3];              \
        {                                                                      \
            int tp = (T) + 2; if (tp > 511) tp = 511;                          \
            _Pragma("unroll")                                                  \
            for (int s = 0; s < 4; ++s) PGV[s] = pg4[tp * 128 + s * 32 + pgo]; \
        }                                                                      \
        _Pragma("unroll")                                                      \
        for (int kt = 0; kt < 4; ++kt) {                                       \
            a0 = __builtin_amdgcn_mfma_f32_16x16x32_f16(afrag[kt][0], bfrag[kt], a0, 0, 0, 0); \
            a1 = __builtin_amdgcn_mfma_f32_16x16x32_f16(afrag[kt][1], bfrag[kt], a1, 0, 0, 0); \
            a2 = __builtin_amdgcn_mfma_f32_16x16x32_f16(afrag[kt][2], bfrag[kt], a2, 0, 0, 0); \
            a3 = __builtin_amdgcn_mfma_f32_16x16x32_f16(afrag[kt][3], bfrag[kt], a3, 0, 0, 0); \
        }                                                                      \
        /* lane-parallel activation: this lane's gate value a_{sgate}[r] */    \
        float t0 = (r == 0) ? a0[0] : (r == 1) ? a0[1] : (r == 2) ? a0[2] : a0[3]; \
        float t1 = (r == 0) ? a1[0] : (r == 1) ? a1[1] : (r == 2) ? a1[2] : a1[3]; \
        float t2 = (r == 0) ? a2[0] : (r == 1) ? a2[1] : (r == 2) ? a2[2] : a2[3]; \
        float t3 = (r == 0) ? a3[0] : (r == 1) ? a3[1] : (r == 2) ? a3[2] : a3[3]; \
        float x = (sgate == 0) ? t0 : (sgate == 1) ? t1 : (sgate == 2) ? t2 : t3; \
        float ee = __expf(isg ? (2.f * x) : (-x));                             \
        float nl = isg ? (1.f - __fdividef(2.f, ee + 1.f))                     \
                       : __fdividef(1.f, 1.f + ee);                            \
        float f_ = __shfl_xor(nl, 4, 64);                                      \
        float g_ = __shfl_xor(nl, 8, 64);                                      \
        float o_ = __shfl_xor(nl, 12, 64);                                     \
        cst = f_ * cst + nl * g_;            /* owners: nl == i-gate */        \
        float h = o_ * ftanh(cst);                                             \
        if (wlane) {                                                           \
            outp[(size_t)(T) * HD] = h;                                        \
            hist[(WRS) * 136 + unit] = (_Float16)h;                            \
        }                                                                      \
        asm volatile("s_waitcnt lgkmcnt(0)" ::: "memory");                     \
        __builtin_amdgcn_sched_barrier(0);                                     \
        __builtin_amdgcn_s_barrier();                                          \
        __builtin_amdgcn_sched_barrier(0);                                     \
    }

#define PROJ_BATCH(P, TBASE)                                                   \
    {                                                                          \
        const _Float16* hb = hist + ((P) * 16 + li) * 136 + g * 8;             \
        half8 bb0 = *(const half8*)(hb + 0 * 32);                              \
        half8 bb1 = *(const half8*)(hb + 1 * 32);                              \
        half8 bb2 = *(const half8*)(hb + 2 * 32);                              \
        half8 bb3 = *(const half8*)(hb + 3 * 32);                              \
        f32x4 pa = {0.f, 0.f, 0.f, 0.f};                                       \
        pa = __builtin_amdgcn_mfma_f32_16x16x32_f16(afragW[0], bb0, pa, 0, 0, 0); \
        pa = __builtin_amdgcn_mfma_f32_16x16x32_f16(afragW[1], bb1, pa, 0, 0, 0); \
        pa = __builtin_amdgcn_mfma_f32_16x16x32_f16(afragW[2], bb2, pa, 0, 0, 0); \
        pa = __builtin_amdgcn_mfma_f32_16x16x32_f16(afragW[3], bb3, pa, 0, 0, 0); \
        float* pp = proj + (size_t)seq * LLEN * HD                             \
                  + (size_t)((TBASE) + li) * HD + w * 16 + g * 4;              \
        *(f32x4*)pp = pa;                                                      \
        pmr0 = fmaxf(pmr0, pa[0]);                                             \
        pmr1 = fmaxf(pmr1, pa[1]);                                             \
        pmr2 = fmaxf(pmr2, pa[2]);                                             \
        pmr3 = fmaxf(pmr3, pa[3]);                                             \
    }

    #pragma unroll 1
    for (int tto = 0; tto < 16; ++tto) {
        const int tb = tto * 32;
        #pragma unroll
        for (int u = 0; u < 16; ++u) {
            const int t0 = tb + u * 2;
            LSTM_STEP(t0,     pgA, (2 * u + 31) & 31, 2 * u);
            LSTM_STEP(t0 + 1, pgB, 2 * u, 2 * u + 1);
            if (u == 7)  PROJ_BATCH(0, tb);
            if (u == 15) PROJ_BATCH(1, tb + 16);
        }
    }
#undef LSTM_STEP
#undef PROJ_BATCH

    // mx: reduce running max over the 16 li lanes (time slices), store per row
    #pragma unroll
    for (int m = 1; m <= 8; m <<= 1) {
        pmr0 = fmaxf(pmr0, __shfl_xor(pmr0, m, 64));
        pmr1 = fmaxf(pmr1, __shfl_xor(pmr1, m, 64));
        pmr2 = fmaxf(pmr2, __shfl_xor(pmr2, m, 64));
        pmr3 = fmaxf(pmr3, __shfl_xor(pmr3, m, 64));
    }
    if (li == 0) {
        mx[seq * HD + w * 16 + g * 4 + 0] = pmr0;
        mx[seq * HD + w * 16 + g * 4 + 1] = pmr1;
        mx[seq * HD + w * 16 + g * 4 + 2] = pmr2;
        mx[seq * HD + w * 16 + g * 4 + 3] = pmr3;
    }
}

// ---------------- K45a: partial one-pass attention. 32 WGs ----------------
__global__ __launch_bounds__(512) void k45a_attn(
    const float* __restrict__ lstm, const float* __restrict__ proj,
    const float* __restrict__ mx, const float* __restrict__ ba,
    const float* __restrict__ wq, const float* __restrict__ wans,
    float* __restrict__ pn, float* __restrict__ pd)
{
    const int bid = blockIdx.x;          // 0..31
    const int chunk = bid & 3, sb = bid >> 2;
    const int s = sb >> 2, b = sb & 3;
    const int tid = threadIdx.x;
    const int wave = tid >> 6, lane = tid & 63;

    __shared__ float nred[8][128];
    __shared__ float dred[8];

    const float* wv = (s == 0) ? wq : wans;
    const float* lb = lstm + (size_t)sb * LLEN * HD;
    const float* po = proj + (size_t)((1 - s) * 4 + b) * LLEN * HD;

    const float mb1 = mx[sb * HD + lane] + ba[lane];
    const float mb2 = mx[sb * HD + lane + 64] + ba[lane + 64];
    const float wv1a = wv[lane], wv1b = wv[lane + 64];
    const float wv2a = wv[128 + lane], wv2b = wv[192 + lane];

    float n1 = 0.f, n2 = 0.f, den = 0.f;
    #pragma unroll 4
    for (int jj = 0; jj < 16; ++jj) {
        const int j = chunk * 128 + wave + jj * 8;
        float L1 = lb[(size_t)j * HD + lane];
        float L2 = lb[(size_t)j * HD + lane + 64];
        float P1 = po[(size_t)j * HD + lane];
        float P2 = po[(size_t)j * HD + lane + 64];
        float r1 = ftanh(mb1 + P1), r2 = ftanh(mb2 + P2);
        float sc = L1 * wv1a + L2 * wv1b + r1 * wv2a + r2 * wv2b;
        #pragma unroll
        for (int o = 32; o; o >>= 1) sc += __shfl_xor(sc, o, 64);
        float e = __expf(sc);
        den += e;
        n1 += e * r1;
        n2 += e * r2;
    }
    nred[wave][lane] = n1;
    nred[wave][lane + 64] = n2;
    if (lane == 0) dred[wave] = den;
    __syncthreads();

    if (tid < 128) {
        float s8 = 0.f;
        #pragma unroll
        for (int i = 0; i < 8; ++i) s8 += nred[i][tid];
        pn[bid * 128 + tid] = s8;
    }
    if (tid == 128) {
        float dd = 0.f;
        #pragma unroll
        for (int i = 0; i < 8; ++i) dd += dred[i];
        pd[bid] = dd;
    }
}

// ---------------- K45b: merge partials + classifier + log_softmax. 4 WGs ----------------
__global__ __launch_bounds__(256) void k45b_final(
    const float* __restrict__ pn, const float* __restrict__ pd,
    const float* __restrict__ wlast, const float* __restrict__ blast,
    float* __restrict__ outp)
{
    const int b = blockIdx.x;            // 0..3
    const int tid = threadIdx.x;
    __shared__ float feats[2][128];
    __shared__ float cls[256];

    {
        const int ss = tid >> 7, h = tid & 127;
        const int base = (ss * 4 + b) * 4;
        float num = pn[(base + 0) * 128 + h] + pn[(base + 1) * 128 + h]
                  + pn[(base + 2) * 128 + h] + pn[(base + 3) * 128 + h];
        float dd  = pd[base + 0] + pd[base + 1] + pd[base + 2] + pd[base + 3];
        feats[ss][h] = num / dd;
    }
    __syncthreads();

    if (tid < 128) {
        float f0 = feats[0][tid], f1 = feats[1][tid];
        cls[tid]       = f0 * wlast[tid * 2 + 0] + f1 * wlast[(128 + tid) * 2 + 0];
        cls[128 + tid] = f0 * wlast[tid * 2 + 1] + f1 * wlast[(128 + tid) * 2 + 1];
    }
    __syncthreads();
    if (tid < 64) {
        float a0 = cls[tid] + cls[tid + 64];
        float a1 = cls[128 + tid] + cls[192 + tid];
        #pragma unroll
        for (int o = 32; o; o >>= 1) {
            a0 += __shfl_down(a0, o, 64);
            a1 += __shfl_down(a1, o, 64);
        }
        if (tid == 0) {
            float l0 = blast[0] + a0, l1 = blast[1] + a1;
            float mxl = fmaxf(l0, l1);
            float lse = mxl + logf(__expf(l0 - mxl) + __expf(l1 - mxl));
            outp[b * 2 + 0] = l0 - lse;
            outp[b * 2 + 1] = l1 - lse;
            outp[8 + b]     = (l1 > l0) ? 1.f : 0.f;
        }
    }
}

extern "C" void kernel_launch(void* const* d_in, const int* in_sizes, int n_in,
                              void* d_out, int out_size, void* d_ws, size_t ws_size,
                              hipStream_t stream)
{
    const int*   qc    = (const int*)d_in[0];
    const int*   ac    = (const int*)d_in[1];
    const float* emb   = (const float*)d_in[2];
    const float* wih   = (const float*)d_in[3];
    const float* whh   = (const float*)d_in[4];
    const float* bl    = (const float*)d_in[5];
    const float* wa    = (const float*)d_in[6];
    const float* ba    = (const float*)d_in[7];
    const float* wq    = (const float*)d_in[8];
    const float* wans  = (const float*)d_in[10];
    const float* wlast = (const float*)d_in[12];
    const float* blast = (const float*)d_in[13];

    float* ws   = (float*)d_ws;
    float* preg = ws;
    float* lstm = ws + OFF_LSTM;
    float* proj = ws + OFF_PROJ;
    float* mx   = ws + OFF_MX;
    float* pn   = ws;          // preg region is dead after k2
    float* pd   = ws + 4096;

    k1_gemm<<<dim3(64, 8), 256, 0, stream>>>(qc, ac, emb, wih, bl, preg);
    k2_lstm_mfma<<<8, 512, 0, stream>>>(whh, preg, wa, lstm, proj, mx);
    k45a_attn<<<32, 512, 0, stream>>>(lstm, proj, mx, ba, wq, wans, pn, pd);
    k45b_final<<<4, 256, 0, stream>>>(pn, pd, wlast, blast, (float*)d_out);
}

// Round 15
// 377.320 us; speedup vs baseline: 2.1732x; 1.0120x over previous
//
#include <hip/hip_runtime.h>
#include <hip/hip_bf16.h>

#define EMBED 300
#define HD    128
#define LLEN  512
#define G4    512   // 4*H

// Workspace layout (floats):
// preg [2][4][512][512] @0 (dead after k2; k45a partials reuse it)
#define OFF_LSTM 2097152
#define OFF_PROJ 2621440
#define OFF_MX   3145728

typedef _Float16 half8 __attribute__((ext_vector_type(8)));
typedef float    f32x4 __attribute__((ext_vector_type(4)));

__device__ __forceinline__ float fsig(float x) {
    return __fdividef(1.f, 1.f + __expf(-x));
}
__device__ __forceinline__ float ftanh(float x) {
    return 1.f - __fdividef(2.f, __expf(2.f * x) + 1.f);
}

// ---------------- K1: embedding gather + X @ W_ih + b via MFMA. ----------------
// A = Wih^T frags (static, 2 j-subtiles/wave), B = emb rows (f16), D col=li -> row,
// rows g*4+r -> j. Same verified fragment maps as k2. Grid (4,128) x 256.
__global__ __launch_bounds__(256) void k1_gemm(
    const int* __restrict__ qc, const int* __restrict__ ac,
    const float* __restrict__ emb, const float* __restrict__ wih,
    const float* __restrict__ bl, float* __restrict__ preg)
{
    const int bx = blockIdx.x;       // j-tile 0..3 (128 j each)
    const int by = blockIdx.y;       // row-tile 0..127 (32 rows each)
    const int tid = threadIdx.x;
    const int w = tid >> 6;          // wave 0..3
    const int l = tid & 63;
    const int li = l & 15, g = l >> 4;
    const int j0 = bx * 128 + w * 32;       // this wave: j-subtiles j0, j0+16

    // A fragments: A[m=li][k=kt*32+g*8+e] = Wih[k][j0+js*16+li]
    half8 afragK[2][10];
    #pragma unroll
    for (int js = 0; js < 2; ++js) {
        #pragma unroll
        for (int kt = 0; kt < 10; ++kt) {
            half8 v;
            #pragma unroll
            for (int e = 0; e < 8; ++e) {
                int k = kt * 32 + g * 8 + e;
                v[e] = (k < 300) ? (_Float16)wih[k * G4 + j0 + js * 16 + li]
                                 : (_Float16)0.f;
            }
            afragK[js][kt] = v;
        }
    }
    const int jc0 = j0 + g * 4, jc1 = j0 + 16 + g * 4;
    const f32x4 bias0 = *(const f32x4*)(bl + jc0);
    const f32x4 bias1 = *(const f32x4*)(bl + jc1);

    #pragma unroll 1
    for (int ns = 0; ns < 2; ++ns) {
        const int row = by * 32 + ns * 16 + li;
        const int c = row >> 11, b = (row >> 9) & 3, t = row & 511;
        const int tok = (c == 0 ? qc : ac)[b * LLEN + t];
        const float* er = emb + (size_t)tok * EMBED;   // 16B-aligned (300*4B = 75*16)
        f32x4 acc0 = {0.f, 0.f, 0.f, 0.f}, acc1 = {0.f, 0.f, 0.f, 0.f};
        #pragma unroll
        for (int kt = 0; kt < 10; ++kt) {
            const int kbase = kt * 32 + g * 8;
            half8 bv;
            if (kt < 9) {
                float4 u0 = *(const float4*)(er + kbase);
                float4 u1 = *(const float4*)(er + kbase + 4);
                bv[0] = (_Float16)u0.x; bv[1] = (_Float16)u0.y;
                bv[2] = (_Float16)u0.z; bv[3] = (_Float16)u0.w;
                bv[4] = (_Float16)u1.x; bv[5] = (_Float16)u1.y;
                bv[6] = (_Float16)u1.z; bv[7] = (_Float16)u1.w;
            } else {
                #pragma unroll
                for (int e = 0; e < 8; ++e) {
                    int k = kbase + e;
                    bv[e] = (k < 300) ? (_Float16)er[k] : (_Float16)0.f;
                }
            }
            acc0 = __builtin_amdgcn_mfma_f32_16x16x32_f16(afragK[0][kt], bv, acc0, 0, 0, 0);
            acc1 = __builtin_amdgcn_mfma_f32_16x16x32_f16(afragK[1][kt], bv, acc1, 0, 0, 0);
        }
        acc0 += bias0;
        acc1 += bias1;
        *(f32x4*)(preg + (size_t)row * G4 + jc0) = acc0;
        *(f32x4*)(preg + (size_t)row * G4 + jc1) = acc1;
    }
}

// ---------------- K2: MFMA LSTM scan + 16-step-batched proj. 8 WGs ----------------
// Round-9 kernel verbatim (proven 347 us profiled).
__global__ __launch_bounds__(512, 1) void k2_lstm_mfma(
    const float* __restrict__ whh, const float* __restrict__ preg,
    const float* __restrict__ wa,
    float* __restrict__ lstm, float* __restrict__ proj, float* __restrict__ mx)
{
    const int seq = blockIdx.x;          // c*4 + b, 0..7
    const int tid = threadIdx.x;
    const int w  = tid >> 6;             // wave 0..7
    const int l  = tid & 63;
    const int li = l & 15;
    const int g  = l >> 4;

    __shared__ __align__(16) _Float16 hist[32 * 136];   // padded rows

    // static gate A fragments: A[m=li][k=kt*32+g*8+e] = Whh[k][mg], mg = s*128+w*16+li
    half8 afrag[4][4];
    #pragma unroll
    for (int s = 0; s < 4; ++s) {
        const int mg = s * 128 + w * 16 + li;
        #pragma unroll
        for (int kt = 0; kt < 4; ++kt) {
            half8 v;
            #pragma unroll
            for (int e = 0; e < 8; ++e)
                v[e] = (_Float16)whh[(kt * 32 + g * 8 + e) * G4 + mg];
            afrag[kt][s] = v;
        }
    }
    // static proj A fragments: A[m=li][k] = Wa[s_side*128 + k][w*16+li]
    const int s_side = seq >> 2;
    half8 afragW[4];
    #pragma unroll
    for (int kt = 0; kt < 4; ++kt) {
        half8 v;
        #pragma unroll
        for (int e = 0; e < 8; ++e)
            v[e] = (_Float16)wa[(s_side * 128 + kt * 32 + g * 8 + e) * 128 + (w * 16 + li)];
        afragW[kt] = v;
    }

    for (int i = tid; i < 32 * 68; i += 512) ((unsigned*)hist)[i] = 0u;

    const f32x4* pg4 = (const f32x4*)(preg + (size_t)seq * LLEN * G4);
    const int pgo = w * 4 + g;           // f32x4 idx; + t*128 + s*32
    const int r   = li & 3;
    const int unit = w * 16 + g * 4 + r;
    const bool wlane = li < 4;
    float* outp = lstm + (size_t)seq * LLEN * HD + unit;
    float cst = 0.f;
    float pmr0 = -1e30f, pmr1 = -1e30f, pmr2 = -1e30f, pmr3 = -1e30f;

    f32x4 pgA[4], pgB[4];
    #pragma unroll
    for (int s = 0; s < 4; ++s) pgA[s] = pg4[0 * 128 + s * 32 + pgo];
    #pragma unroll
    for (int s = 0; s < 4; ++s) pgB[s] = pg4[1 * 128 + s * 32 + pgo];

    __syncthreads();

#define LSTM_STEP(T, PGV, RDS, WRS)                                            \
    {                                                                          \
        half8 bfrag[4];                                                        \
        _Pragma("unroll")                                                      \
        for (int kt = 0; kt < 4; ++kt)                                         \
            bfrag[kt] = *(const half8*)(hist + (RDS) * 136 + kt * 32 + g * 8); \
        f32x4 a0 = PGV[0], a1 = PGV[1], a2 = PGV[2], a3 = PGV[3];              \
        {                                                                      \
            int tp = (T) + 2; if (tp > 511) tp = 511;                          \
            _Pragma("unroll")                                                  \
            for (int s = 0; s < 4; ++s) PGV[s] = pg4[tp * 128 + s * 32 + pgo]; \
        }                                                                      \
        _Pragma("unroll")                                                      \
        for (int kt = 0; kt < 4; ++kt) {                                       \
            a0 = __builtin_amdgcn_mfma_f32_16x16x32_f16(afrag[kt][0], bfrag[kt], a0, 0, 0, 0); \
            a1 = __builtin_amdgcn_mfma_f32_16x16x32_f16(afrag[kt][1], bfrag[kt], a1, 0, 0, 0); \
            a2 = __builtin_amdgcn_mfma_f32_16x16x32_f16(afrag[kt][2], bfrag[kt], a2, 0, 0, 0); \
            a3 = __builtin_amdgcn_mfma_f32_16x16x32_f16(afrag[kt][3], bfrag[kt], a3, 0, 0, 0); \
        }                                                                      \
        float xi = (r == 0) ? a0[0] : (r == 1) ? a0[1] : (r == 2) ? a0[2] : a0[3]; \
        float xf = (r == 0) ? a1[0] : (r == 1) ? a1[1] : (r == 2) ? a1[2] : a1[3]; \
        float xg = (r == 0) ? a2[0] : (r == 1) ? a2[1] : (r == 2) ? a2[2] : a2[3]; \
        float xo = (r == 0) ? a3[0] : (r == 1) ? a3[1] : (r == 2) ? a3[2] : a3[3]; \
        float i_ = fsig(xi), f_ = fsig(xf), g_ = ftanh(xg), o_ = fsig(xo);     \
        cst = f_ * cst + i_ * g_;                                              \
        float h = o_ * ftanh(cst);                                             \
        if (wlane) {                                                           \
            outp[(size_t)(T) * HD] = h;                                        \
            hist[(WRS) * 136 + unit] = (_Float16)h;                            \
        }                                                                      \
        asm volatile("s_waitcnt lgkmcnt(0)" ::: "memory");                     \
        __builtin_amdgcn_sched_barrier(0);                                     \
        __builtin_amdgcn_s_barrier();                                          \
        __builtin_amdgcn_sched_barrier(0);                                     \
    }

    #pragma unroll 1
    for (int tt = 0; tt < 256; ++tt) {
        const int t0 = tt * 2;
        const int slot = t0 & 31;
        LSTM_STEP(t0,     pgA, (slot + 31) & 31, slot);
        LSTM_STEP(t0 + 1, pgB, slot, slot + 1);
        if ((tt & 7) == 7) {
            // batched proj for the window just completed
            const int p = (tt >> 3) & 1;
            const int tbase = t0 - 14;
            const _Float16* hb = hist + (p * 16 + li) * 136;
            half8 bb0 = *(const half8*)(hb + 0 * 32 + g * 8);
            half8 bb1 = *(const half8*)(hb + 1 * 32 + g * 8);
            half8 bb2 = *(const half8*)(hb + 2 * 32 + g * 8);
            half8 bb3 = *(const half8*)(hb + 3 * 32 + g * 8);
            f32x4 pa = {0.f, 0.f, 0.f, 0.f};
            pa = __builtin_amdgcn_mfma_f32_16x16x32_f16(afragW[0], bb0, pa, 0, 0, 0);
            pa = __builtin_amdgcn_mfma_f32_16x16x32_f16(afragW[1], bb1, pa, 0, 0, 0);
            pa = __builtin_amdgcn_mfma_f32_16x16x32_f16(afragW[2], bb2, pa, 0, 0, 0);
            pa = __builtin_amdgcn_mfma_f32_16x16x32_f16(afragW[3], bb3, pa, 0, 0, 0);
            float* pp = proj + (size_t)seq * LLEN * HD
                      + (size_t)(tbase + li) * HD + w * 16 + g * 4;
            *(f32x4*)pp = pa;
            pmr0 = fmaxf(pmr0, pa[0]);
            pmr1 = fmaxf(pmr1, pa[1]);
            pmr2 = fmaxf(pmr2, pa[2]);
            pmr3 = fmaxf(pmr3, pa[3]);
        }
    }
#undef LSTM_STEP

    // mx: reduce running max over the 16 li lanes (time slices), store per row
    #pragma unroll
    for (int m = 1; m <= 8; m <<= 1) {
        pmr0 = fmaxf(pmr0, __shfl_xor(pmr0, m, 64));
        pmr1 = fmaxf(pmr1, __shfl_xor(pmr1, m, 64));
        pmr2 = fmaxf(pmr2, __shfl_xor(pmr2, m, 64));
        pmr3 = fmaxf(pmr3, __shfl_xor(pmr3, m, 64));
    }
    if (li == 0) {
        mx[seq * HD + w * 16 + g * 4 + 0] = pmr0;
        mx[seq * HD + w * 16 + g * 4 + 1] = pmr1;
        mx[seq * HD + w * 16 + g * 4 + 2] = pmr2;
        mx[seq * HD + w * 16 + g * 4 + 3] = pmr3;
    }
}

// ---------------- K45a: partial one-pass attention. 32 WGs ----------------
__global__ __launch_bounds__(512) void k45a_attn(
    const float* __restrict__ lstm, const float* __restrict__ proj,
    const float* __restrict__ mx, const float* __restrict__ ba,
    const float* __restrict__ wq, const float* __restrict__ wans,
    float* __restrict__ pn, float* __restrict__ pd)
{
    const int bid = blockIdx.x;          // 0..31
    const int chunk = bid & 3, sb = bid >> 2;
    const int s = sb >> 2, b = sb & 3;
    const int tid = threadIdx.x;
    const int wave = tid >> 6, lane = tid & 63;

    __shared__ float nred[8][128];
    __shared__ float dred[8];

    const float* wv = (s == 0) ? wq : wans;
    const float* lb = lstm + (size_t)sb * LLEN * HD;
    const float* po = proj + (size_t)((1 - s) * 4 + b) * LLEN * HD;

    const float mb1 = mx[sb * HD + lane] + ba[lane];
    const float mb2 = mx[sb * HD + lane + 64] + ba[lane + 64];
    const float wv1a = wv[lane], wv1b = wv[lane + 64];
    const float wv2a = wv[128 + lane], wv2b = wv[192 + lane];

    float n1 = 0.f, n2 = 0.f, den = 0.f;
    #pragma unroll 4
    for (int jj = 0; jj < 16; ++jj) {
        const int j = chunk * 128 + wave + jj * 8;
        float L1 = lb[(size_t)j * HD + lane];
        float L2 = lb[(size_t)j * HD + lane + 64];
        float P1 = po[(size_t)j * HD + lane];
        float P2 = po[(size_t)j * HD + lane + 64];
        float r1 = ftanh(mb1 + P1), r2 = ftanh(mb2 + P2);
        float sc = L1 * wv1a + L2 * wv1b + r1 * wv2a + r2 * wv2b;
        #pragma unroll
        for (int o = 32; o; o >>= 1) sc += __shfl_xor(sc, o, 64);
        float e = __expf(sc);
        den += e;
        n1 += e * r1;
        n2 += e * r2;
    }
    nred[wave][lane] = n1;
    nred[wave][lane + 64] = n2;
    if (lane == 0) dred[wave] = den;
    __syncthreads();

    if (tid < 128) {
        float s8 = 0.f;
        #pragma unroll
        for (int i = 0; i < 8; ++i) s8 += nred[i][tid];
        pn[bid * 128 + tid] = s8;
    }
    if (tid == 128) {
        float dd = 0.f;
        #pragma unroll
        for (int i = 0; i < 8; ++i) dd += dred[i];
        pd[bid] = dd;
    }
}

// ---------------- K45b: merge partials + classifier + log_softmax. 4 WGs ----------------
__global__ __launch_bounds__(256) void k45b_final(
    const float* __restrict__ pn, const float* __restrict__ pd,
    const float* __restrict__ wlast, const float* __restrict__ blast,
    float* __restrict__ outp)
{
    const int b = blockIdx.x;            // 0..3
    const int tid = threadIdx.x;
    __shared__ float feats[2][128];
    __shared__ float cls[256];

    {
        const int ss = tid >> 7, h = tid & 127;
        const int base = (ss * 4 + b) * 4;
        float num = pn[(base + 0) * 128 + h] + pn[(base + 1) * 128 + h]
                  + pn[(base + 2) * 128 + h] + pn[(base + 3) * 128 + h];
        float dd  = pd[base + 0] + pd[base + 1] + pd[base + 2] + pd[base + 3];
        feats[ss][h] = num / dd;
    }
    __syncthreads();

    if (tid < 128) {
        float f0 = feats[0][tid], f1 = feats[1][tid];
        cls[tid]       = f0 * wlast[tid * 2 + 0] + f1 * wlast[(128 + tid) * 2 + 0];
        cls[128 + tid] = f0 * wlast[tid * 2 + 1] + f1 * wlast[(128 + tid) * 2 + 1];
    }
    __syncthreads();
    if (tid < 64) {
        float a0 = cls[tid] + cls[tid + 64];
        float a1 = cls[128 + tid] + cls[192 + tid];
        #pragma unroll
        for (int o = 32; o; o >>= 1) {
            a0 += __shfl_down(a0, o, 64);
            a1 += __shfl_down(a1, o, 64);
        }
        if (tid == 0) {
            float l0 = blast[0] + a0, l1 = blast[1] + a1;
            float mxl = fmaxf(l0, l1);
            float lse = mxl + logf(__expf(l0 - mxl) + __expf(l1 - mxl));
            outp[b * 2 + 0] = l0 - lse;
            outp[b * 2 + 1] = l1 - lse;
            outp[8 + b]     = (l1 > l0) ? 1.f : 0.f;
        }
    }
}

extern "C" void kernel_launch(void* const* d_in, const int* in_sizes, int n_in,
                              void* d_out, int out_size, void* d_ws, size_t ws_size,
                              hipStream_t stream)
{
    const int*   qc    = (const int*)d_in[0];
    const int*   ac    = (const int*)d_in[1];
    const float* emb   = (const float*)d_in[2];
    const float* wih   = (const float*)d_in[3];
    const float* whh   = (const float*)d_in[4];
    const float* bl    = (const float*)d_in[5];
    const float* wa    = (const float*)d_in[6];
    const float* ba    = (const float*)d_in[7];
    const float* wq    = (const float*)d_in[8];
    const float* wans  = (const float*)d_in[10];
    const float* wlast = (const float*)d_in[12];
    const float* blast = (const float*)d_in[13];

    float* ws   = (float*)d_ws;
    float* preg = ws;
    float* lstm = ws + OFF_LSTM;
    float* proj = ws + OFF_PROJ;
    float* mx   = ws + OFF_MX;
    float* pn   = ws;          // preg region is dead after k2
    float* pd   = ws + 4096;

    k1_gemm<<<dim3(4, 128), 256, 0, stream>>>(qc, ac, emb, wih, bl, preg);
    k2_lstm_mfma<<<8, 512, 0, stream>>>(whh, preg, wa, lstm, proj, mx);
    k45a_attn<<<32, 512, 0, stream>>>(lstm, proj, mx, ba, wq, wans, pn, pd);
    k45b_final<<<4, 256, 0, stream>>>(pn, pd, wlast, blast, (float*)d_out);
}